// Round 6
// baseline (495.764 us; speedup 1.0000x reference)
//
#include <hip/hip_runtime.h>
#include <cstdint>
#include <cmath>

// ---------------------------------------------------------------------------
// LlamaAttention round 6: flash occupancy fix (frag-major P buffer, 3 blk/CU)
//   + fast rope (__expf).
//   B=2 L=2048 D=2048 H=16 KV=4 DH=128, causal + key-padding mask, RoPE.
// Pipeline: cast -> fused QKV gemm (128x128, global_load_lds) -> RoPE+bias ->
//           flash (S^T/O^T, balanced pairs) -> O gemm (f32 out).
// MFMA layouts (learn_hip m89/m91): A[m=l15][k=quad*8+j], B[k=quad*8+j][n=l15],
//   C/D: col=l15, row=quad*4+reg.
// R6: Pbuf 18.4KB row-major -> 16KB frag-major (writer scatters into reader's
//     B-frag byte positions; reads = contiguous lane*16B). LDS 54.3->51KB =>
//     3 blocks/CU (was 2). rope powf -> __expf.
// ---------------------------------------------------------------------------

typedef __bf16 bf16_t;
typedef __bf16 bf16x8 __attribute__((ext_vector_type(8)));
typedef __bf16 bf16x4 __attribute__((ext_vector_type(4)));
typedef float  f32x4  __attribute__((ext_vector_type(4)));

#define HQ   16
#define HKV  4
#define GQA  4
#define DHD  128
#define BB   2
#define LL   2048
#define DDIM 2048
#define MINV (-1e15f)

static __device__ __forceinline__ f32x4 mfma16(bf16x8 a, bf16x8 b, f32x4 c) {
  return __builtin_amdgcn_mfma_f32_16x16x32_bf16(a, b, c, 0, 0, 0);
}

static __device__ __forceinline__ void gld16(const bf16_t* g, bf16_t* l) {
  __builtin_amdgcn_global_load_lds(
      (const __attribute__((address_space(1))) void*)g,
      (__attribute__((address_space(3))) void*)l,
      16, 0, 0);
}

// ---------------- f32 -> bf16 cast (5 tensors in one launch) ----------------
struct CastArgs {
  const float* s[5];
  bf16_t* d[5];
  int n[5];
};

__global__ __launch_bounds__(256) void cast5_kernel(CastArgs a) {
  const int t = blockIdx.y;
  const int i8 = (blockIdx.x * 256 + threadIdx.x) * 8;
  if (i8 >= a.n[t]) return;
  const float4* s = (const float4*)(a.s[t] + i8);
  float4 x = s[0], y = s[1];
  bf16x8 o = {(bf16_t)x.x, (bf16_t)x.y, (bf16_t)x.z, (bf16_t)x.w,
              (bf16_t)y.x, (bf16_t)y.y, (bf16_t)y.z, (bf16_t)y.w};
  *(bf16x8*)(a.d[t] + i8) = o;
}

// ---------------------------------------------------------------------------
// Tiled GEMM: C = A(MxK) * W(NxK)^T, 128x128 tile, BK=32 (m97 structure).
// STORE 2: f32 row-major -> C0.
// STORE 3: fused QKV epilogue (N=3072): cols [0,2048) -> C0 bf16 row-major;
//   [2048,2560) -> Ck bf16 row-major (N=512); [2560,3072) -> Cv transposed
//   (B,KV,DH,L) with bf16x4 packed stores along L.
// ---------------------------------------------------------------------------
template <int STORE>
__global__ __launch_bounds__(256) void gemm_tile(const bf16_t* __restrict__ A,
                                                 const bf16_t* __restrict__ W,
                                                 void* __restrict__ C0,
                                                 bf16_t* __restrict__ Ck,
                                                 bf16_t* __restrict__ Cv,
                                                 int M, int N, int K) {
  __shared__ __align__(16) bf16_t As[128 * 32];
  __shared__ __align__(16) bf16_t Bs[128 * 32];
  const int tid  = threadIdx.x;
  const int lane = tid & 63;
  const int wave = tid >> 6;
  const int l15  = lane & 15;
  const int quad = lane >> 4;
  const int m0 = blockIdx.y * 128;
  const int n0 = blockIdx.x * 128;

  const int srow = wave * 32 + (lane >> 2);
  const int scol = (lane & 3) * 8;
  const bf16_t* ag = A + (size_t)(m0 + srow) * K + scol;
  const bf16_t* wg = W + (size_t)(n0 + srow) * K + scol;
  bf16_t* al = As + wave * 1024;
  bf16_t* bl = Bs + wave * 1024;

  const int wm = (wave >> 1) * 64;
  const int wn = (wave & 1) * 64;

  f32x4 acc[4][4];
#pragma unroll
  for (int mi = 0; mi < 4; mi++)
#pragma unroll
    for (int ni = 0; ni < 4; ni++) acc[mi][ni] = {0.f, 0.f, 0.f, 0.f};

  for (int k0 = 0; k0 < K; k0 += 32) {
    __syncthreads();
    gld16(ag + k0, al);
    gld16(ag + k0 + (size_t)16 * K, al + 512);
    gld16(wg + k0, bl);
    gld16(wg + k0 + (size_t)16 * K, bl + 512);
    __syncthreads();
    bf16x8 af[4], bfr[4];
#pragma unroll
    for (int mi = 0; mi < 4; mi++)
      af[mi] = *(const bf16x8*)(As + (wm + mi * 16 + l15) * 32 + quad * 8);
#pragma unroll
    for (int ni = 0; ni < 4; ni++)
      bfr[ni] = *(const bf16x8*)(Bs + (wn + ni * 16 + l15) * 32 + quad * 8);
#pragma unroll
    for (int mi = 0; mi < 4; mi++)
#pragma unroll
      for (int ni = 0; ni < 4; ni++)
        acc[mi][ni] = mfma16(af[mi], bfr[ni], acc[mi][ni]);
  }

  if (STORE == 2) {
    float* C = (float*)C0;
#pragma unroll
    for (int mi = 0; mi < 4; mi++) {
      const int row = m0 + wm + mi * 16 + quad * 4;
#pragma unroll
      for (int ni = 0; ni < 4; ni++) {
        const int col = n0 + wn + ni * 16 + l15;
#pragma unroll
        for (int i = 0; i < 4; i++)
          C[(size_t)(row + i) * N + col] = acc[mi][ni][i];
      }
    }
  } else {  // STORE == 3
    if (n0 < 2048) {
      bf16_t* C = (bf16_t*)C0;
#pragma unroll
      for (int mi = 0; mi < 4; mi++) {
        const int row = m0 + wm + mi * 16 + quad * 4;
#pragma unroll
        for (int ni = 0; ni < 4; ni++) {
          const int col = n0 + wn + ni * 16 + l15;
#pragma unroll
          for (int i = 0; i < 4; i++)
            C[(size_t)(row + i) * 2048 + col] = (bf16_t)acc[mi][ni][i];
        }
      }
    } else if (n0 < 2560) {
#pragma unroll
      for (int mi = 0; mi < 4; mi++) {
        const int row = m0 + wm + mi * 16 + quad * 4;
#pragma unroll
        for (int ni = 0; ni < 4; ni++) {
          const int col = n0 - 2048 + wn + ni * 16 + l15;
#pragma unroll
          for (int i = 0; i < 4; i++)
            Ck[(size_t)(row + i) * 512 + col] = (bf16_t)acc[mi][ni][i];
        }
      }
    } else {
#pragma unroll
      for (int mi = 0; mi < 4; mi++) {
        const int row = m0 + wm + mi * 16 + quad * 4;
        const int b = row >> 11;
        const int l0 = row & (LL - 1);
#pragma unroll
        for (int ni = 0; ni < 4; ni++) {
          const int kvcol = n0 - 2560 + wn + ni * 16 + l15;
          const int kvh = kvcol >> 7, d = kvcol & 127;
          bf16x4 w4 = {(bf16_t)acc[mi][ni][0], (bf16_t)acc[mi][ni][1],
                       (bf16_t)acc[mi][ni][2], (bf16_t)acc[mi][ni][3]};
          *(bf16x4*)(Cv + ((size_t)(b * HKV + kvh) * DHD + d) * LL + l0) = w4;
        }
      }
    }
  }
}

// In-place RoPE on q,k + padding-bias fill. One thread per (b,l,head,dpair).
__global__ void rope_kernel(bf16_t* __restrict__ q, bf16_t* __restrict__ k,
                            const int* __restrict__ amask, float* __restrict__ bias) {
  const int nq = BB * LL * HQ * 64;
  const int nk = BB * LL * HKV * 64;
  int id = blockIdx.x * blockDim.x + threadIdx.x;
  if (id >= nq + nk) {
    int id2 = id - (nq + nk);
    if (id2 < BB * LL) bias[id2] = (amask[id2] == 0) ? MINV : 0.0f;
    return;
  }
  bf16_t* base;
  int heads, idx;
  if (id < nq) { base = q; heads = HQ; idx = id; }
  else         { base = k; heads = HKV; idx = id - nq; }
  int d = idx & 63; idx >>= 6;
  int hh = idx % heads;
  int bl = idx / heads;      // b*LL + l
  int l = bl & (LL - 1);
  bf16_t* p = base + ((size_t)bl * heads + hh) * DHD + d;
  float x1 = (float)p[0];
  float x2 = (float)p[64];
  // invf = 10000^(-d/64) = exp(-d * ln(10000)/64)   (R6: __expf, was powf)
  float invf = __expf(-(float)d * 0.14391156862532788f);
  float fr = (float)l * invf;
  float s, c;
  __sincosf(fr, &s, &c);
  p[0]  = (bf16_t)(x1 * c - x2 * s);
  p[64] = (bf16_t)(x2 * c + x1 * s);
}

// ---------------------------------------------------------------------------
// Flash attention, balanced pairs + LDS staging + frag-major P (R6).
// Block: 256 threads = 4 waves; block c handles 64-row q-tiles {c, 31-c};
// wave w owns rows {c*64+w*16, (31-c)*64+w*16}. KV round = 64 keys in LDS.
// P layout (per wave, per qt, 1 KB per frag): writer lane (quad,l15), scores
// for keys kt*16+quad*4+i, qrow l15, stores bf16x4 at elem offset
//   f*512 + ((kt&1)*2 + (quad>>1))*128 + l15*8 + (quad&1)*4   (f = kt>>1)
// reader lane reads B-frag = 16B contiguous at lane*8 elems (+f*512).
// ---------------------------------------------------------------------------
#define KSTR 136   // K row stride (128 + 8 elements pad)
#define VSTR 72    // V^T row stride (64 + 8 elements pad)

__global__ __launch_bounds__(256, 3) void flash_attn2(const bf16_t* __restrict__ q,
                                                      const bf16_t* __restrict__ k,
                                                      const bf16_t* __restrict__ vt,
                                                      const float* __restrict__ bias,
                                                      bf16_t* __restrict__ o) {
  __shared__ __align__(16) bf16_t Kbuf[64 * KSTR];        // 17.4 KB
  __shared__ __align__(16) bf16_t Vbuf[128 * VSTR];       // 18.4 KB
  __shared__ __align__(16) bf16_t Pbuf[4 * 2 * 1024];     // 16 KB frag-major

  const int tid  = threadIdx.x;
  const int lane = tid & 63;
  const int wave = tid >> 6;
  const int l15  = lane & 15;
  const int quad = lane >> 4;

  const int c  = blockIdx.x >> 5;          // 0..15 : tile pair {c, 31-c}
  const int bh = blockIdx.x & 31;
  const int b  = bh >> 4;
  const int h  = bh & 15;
  const int kv = h >> 2;

  const int q0[2] = { c * 64 + wave * 16, (31 - c) * 64 + wave * 16 };
  const int nrounds = 32 - c;
  const float kScale = 0.08838834764831845f;  // 1/sqrt(128)

  bf16x8 qf[2][4];
#pragma unroll
  for (int qt = 0; qt < 2; qt++) {
    const bf16_t* qb = q + ((size_t)(b * LL + q0[qt] + l15)) * (HQ * DHD) + h * DHD + quad * 8;
#pragma unroll
    for (int t = 0; t < 4; t++) qf[qt][t] = *(const bf16x8*)(qb + 32 * t);
  }

  f32x4 acc[8][2];
#pragma unroll
  for (int mt = 0; mt < 8; mt++)
#pragma unroll
    for (int qt = 0; qt < 2; qt++) acc[mt][qt] = {0.f, 0.f, 0.f, 0.f};
  float m_i[2] = {-1e30f, -1e30f};
  float l_i[2] = {0.f, 0.f};

  const bf16_t* kg_base = k + ((size_t)(b * LL)) * (HKV * DHD) + kv * DHD;
  const bf16_t* vg_base = vt + ((size_t)(b * HKV + kv) * DHD) * LL;
  const float*  bias_b  = bias + b * LL;

  const int krow = tid >> 4, kch = tid & 15;
  const int vrow = tid >> 3, vch = tid & 7;

  for (int r = 0; r < nrounds; r++) {
    const int j0 = r * 64;
    {
      const bf16_t* kg = kg_base + (size_t)(j0 + krow) * (HKV * DHD) + kch * 8;
      const bf16_t* vg = vg_base + (size_t)vrow * LL + j0 + vch * 8;
      bf16x8 kl[4], vl[4];
#pragma unroll
      for (int p = 0; p < 4; p++) kl[p] = *(const bf16x8*)(kg + (size_t)p * 16 * (HKV * DHD));
#pragma unroll
      for (int p = 0; p < 4; p++) vl[p] = *(const bf16x8*)(vg + (size_t)p * 32 * LL);
      __syncthreads();
#pragma unroll
      for (int p = 0; p < 4; p++) *(bf16x8*)(Kbuf + (krow + p * 16) * KSTR + kch * 8) = kl[p];
#pragma unroll
      for (int p = 0; p < 4; p++) *(bf16x8*)(Vbuf + (vrow + p * 32) * VSTR + vch * 8) = vl[p];
      __syncthreads();
    }
    const bool act_a = (r <= c);

    f32x4 s[2][4];
#pragma unroll
    for (int kt = 0; kt < 4; kt++) {
      const bf16_t* kr = Kbuf + (kt * 16 + l15) * KSTR + quad * 8;
      f32x4 s0 = {0.f, 0.f, 0.f, 0.f};
      f32x4 s1 = {0.f, 0.f, 0.f, 0.f};
#pragma unroll
      for (int t = 0; t < 4; t++) {
        bf16x8 kf = *(const bf16x8*)(kr + t * 32);
        if (act_a) s0 = mfma16(kf, qf[0][t], s0);
        s1 = mfma16(kf, qf[1][t], s1);
      }
      s[0][kt] = s0; s[1][kt] = s1;
    }

    f32x4 bv[4];
#pragma unroll
    for (int kt = 0; kt < 4; kt++) bv[kt] = *(const f32x4*)(bias_b + j0 + kt * 16 + quad * 4);

    bf16x8 pf[2][2];
#pragma unroll
    for (int qt = 0; qt < 2; qt++) {
      if (qt == 0 && !act_a) continue;
      const int qrow = q0[qt] + l15;
      const bool diag = (j0 + 63 > q0[qt]);    // mask iff max key > MIN row (R4 fix)
      float mx = -1e30f;
#pragma unroll
      for (int kt = 0; kt < 4; kt++) {
        f32x4 sv = s[qt][kt];
#pragma unroll
        for (int i = 0; i < 4; i++) {
          float x = sv[i] + bv[kt][i];
          if (diag) {
            int key = j0 + kt * 16 + quad * 4 + i;
            if (key > qrow) x = MINV;
          }
          sv[i] = x;
          mx = fmaxf(mx, x);
        }
        s[qt][kt] = sv;
      }
      mx = fmaxf(mx, __shfl_xor(mx, 16));
      mx = fmaxf(mx, __shfl_xor(mx, 32));
      const float mn = fmaxf(m_i[qt], mx);
      const float alpha = __expf((m_i[qt] - mn) * kScale);
      m_i[qt] = mn;
      float sum = 0.f;
      // frag-major P write (R6): per kt one b64 store into reader's frag bytes
      bf16_t* pw = Pbuf + wave * 2048 + qt * 1024 + l15 * 8 + (quad & 1) * 4;
#pragma unroll
      for (int kt = 0; kt < 4; kt++) {
        f32x4 sv = s[qt][kt];
        bf16x4 p4;
#pragma unroll
        for (int i = 0; i < 4; i++) {
          float p = __expf((sv[i] - mn) * kScale);
          sum += p;
          p4[i] = (bf16_t)p;
        }
        *(bf16x4*)(pw + (kt >> 1) * 512 + ((kt & 1) * 2 + (quad >> 1)) * 128) = p4;
      }
      sum += __shfl_xor(sum, 16);
      sum += __shfl_xor(sum, 32);
      l_i[qt] = l_i[qt] * alpha + sum;
#pragma unroll
      for (int mt = 0; mt < 8; mt++) {
        acc[mt][qt][0] *= alpha; acc[mt][qt][1] *= alpha;
        acc[mt][qt][2] *= alpha; acc[mt][qt][3] *= alpha;
      }
      // frag-major P read: contiguous 16B per lane (same-wave DS in-order)
      const bf16_t* pr = Pbuf + wave * 2048 + qt * 1024 + lane * 8;
      pf[qt][0] = *(const bf16x8*)(pr);
      pf[qt][1] = *(const bf16x8*)(pr + 512);
    }

#pragma unroll
    for (int mt = 0; mt < 8; mt++) {
      const bf16_t* vr = Vbuf + (mt * 16 + l15) * VSTR + quad * 8;
      bf16x8 vf0 = *(const bf16x8*)(vr);
      bf16x8 vf1 = *(const bf16x8*)(vr + 32);
      if (act_a) {
        acc[mt][0] = mfma16(vf0, pf[0][0], acc[mt][0]);
        acc[mt][0] = mfma16(vf1, pf[0][1], acc[mt][0]);
      }
      acc[mt][1] = mfma16(vf0, pf[1][0], acc[mt][1]);
      acc[mt][1] = mfma16(vf1, pf[1][1], acc[mt][1]);
    }
  }

#pragma unroll
  for (int qt = 0; qt < 2; qt++) {
    const float invl = 1.0f / l_i[qt];
    bf16_t* ob = o + ((size_t)(b * LL + q0[qt] + l15)) * (HQ * DHD) + h * DHD + quad * 4;
#pragma unroll
    for (int mt = 0; mt < 8; mt++) {
      f32x4 a = acc[mt][qt];
      bf16x4 w = {(bf16_t)(a[0] * invl), (bf16_t)(a[1] * invl),
                  (bf16_t)(a[2] * invl), (bf16_t)(a[3] * invl)};
      *(bf16x4*)(ob + mt * 16) = w;
    }
  }
}

extern "C" void kernel_launch(void* const* d_in, const int* in_sizes, int n_in,
                              void* d_out, int out_size, void* d_ws, size_t ws_size,
                              hipStream_t stream) {
  const float* hidden = (const float*)d_in[0];
  const int*   amask  = (const int*)d_in[1];
  const float* Wq     = (const float*)d_in[2];
  const float* Wk     = (const float*)d_in[3];
  const float* Wv     = (const float*)d_in[4];
  const float* Wo     = (const float*)d_in[5];
  float* out = (float*)d_out;

  const int M = BB * LL;           // 4096
  const size_t MB = 1u << 20;
  char* ws = (char*)d_ws;
  bf16_t* hid_b   = (bf16_t*)(ws);            // 16 MB  (B,L,D)
  bf16_t* q_ws    = (bf16_t*)(ws + 16 * MB);  // 16 MB
  bf16_t* attn_ws = (bf16_t*)(ws + 32 * MB);  // 16 MB
  bf16_t* k_ws    = (bf16_t*)(ws + 48 * MB);  //  4 MB
  bf16_t* vt_ws   = (bf16_t*)(ws + 52 * MB);  //  4 MB
  bf16_t* wqkv_b  = (bf16_t*)(ws + 56 * MB);  // 12 MB: Wq(8) + Wk(2) + Wv(2)
  bf16_t* wq_b    = wqkv_b;
  bf16_t* wk_b    = (bf16_t*)(ws + 64 * MB);
  bf16_t* wv_b    = (bf16_t*)(ws + 66 * MB);
  bf16_t* wo_b    = (bf16_t*)(ws + 68 * MB);  //  8 MB
  float*  bias_ws = (float*)(ws);             // 16 KB, aliases hid_b

  CastArgs ca;
  ca.s[0] = hidden; ca.d[0] = hid_b; ca.n[0] = BB * LL * DDIM;
  ca.s[1] = Wq;     ca.d[1] = wq_b;  ca.n[1] = HQ * DHD * DDIM;
  ca.s[2] = Wk;     ca.d[2] = wk_b;  ca.n[2] = HKV * DHD * DDIM;
  ca.s[3] = Wv;     ca.d[3] = wv_b;  ca.n[3] = HKV * DHD * DDIM;
  ca.s[4] = Wo;     ca.d[4] = wo_b;  ca.n[4] = DDIM * DDIM;
  {
    int maxn = BB * LL * DDIM;
    dim3 g((maxn / 8 + 255) / 256, 5);
    cast5_kernel<<<g, 256, 0, stream>>>(ca);
  }

  gemm_tile<3><<<dim3(3072 / 128, M / 128), 256, 0, stream>>>(
      hid_b, wqkv_b, q_ws, k_ws, vt_ws, M, 3072, DDIM);

  {
    int total = BB * LL * (HQ + HKV) * 64 + BB * LL;
    rope_kernel<<<(total + 255) / 256, 256, 0, stream>>>(q_ws, k_ws, amask, bias_ws);
  }

  flash_attn2<<<BB * HQ * 16, 256, 0, stream>>>(q_ws, k_ws, vt_ws, bias_ws, attn_ws);

  gemm_tile<2><<<dim3(DDIM / 128, M / 128), 256, 0, stream>>>(
      attn_ws, wo_b, (void*)out, nullptr, nullptr, M, DDIM, DDIM);
}

// Round 7
// 330.207 us; speedup vs baseline: 1.5014x; 1.5014x over previous
//
#include <hip/hip_runtime.h>
#include <cstdint>
#include <cmath>

// ---------------------------------------------------------------------------
// LlamaAttention round 7: R6 minus the spill — launch_bounds back to (256,2).
//   B=2 L=2048 D=2048 H=16 KV=4 DH=128, causal + key-padding mask, RoPE.
// Pipeline: cast -> fused QKV gemm (128x128, global_load_lds) -> RoPE+bias ->
//           flash (S^T/O^T, balanced pairs, frag-major P) -> O gemm (f32 out).
// MFMA layouts (learn_hip m89/m91): A[m=l15][k=quad*8+j], B[k=quad*8+j][n=l15],
//   C/D: col=l15, row=quad*4+reg.
// R7 LESSON: __launch_bounds__(256,3) forced VGPR 120->84 => acc spills to
//   scratch => 585 MB HBM writes, 3x slowdown. Keep (256,2); LDS=51KB gives
//   3 blocks/CU at runtime anyway (160/51), since VGPR=120 allows 4 waves/SIMD.
// ---------------------------------------------------------------------------

typedef __bf16 bf16_t;
typedef __bf16 bf16x8 __attribute__((ext_vector_type(8)));
typedef __bf16 bf16x4 __attribute__((ext_vector_type(4)));
typedef float  f32x4  __attribute__((ext_vector_type(4)));

#define HQ   16
#define HKV  4
#define GQA  4
#define DHD  128
#define BB   2
#define LL   2048
#define DDIM 2048
#define MINV (-1e15f)

static __device__ __forceinline__ f32x4 mfma16(bf16x8 a, bf16x8 b, f32x4 c) {
  return __builtin_amdgcn_mfma_f32_16x16x32_bf16(a, b, c, 0, 0, 0);
}

static __device__ __forceinline__ void gld16(const bf16_t* g, bf16_t* l) {
  __builtin_amdgcn_global_load_lds(
      (const __attribute__((address_space(1))) void*)g,
      (__attribute__((address_space(3))) void*)l,
      16, 0, 0);
}

// ---------------- f32 -> bf16 cast (5 tensors in one launch) ----------------
struct CastArgs {
  const float* s[5];
  bf16_t* d[5];
  int n[5];
};

__global__ __launch_bounds__(256) void cast5_kernel(CastArgs a) {
  const int t = blockIdx.y;
  const int i8 = (blockIdx.x * 256 + threadIdx.x) * 8;
  if (i8 >= a.n[t]) return;
  const float4* s = (const float4*)(a.s[t] + i8);
  float4 x = s[0], y = s[1];
  bf16x8 o = {(bf16_t)x.x, (bf16_t)x.y, (bf16_t)x.z, (bf16_t)x.w,
              (bf16_t)y.x, (bf16_t)y.y, (bf16_t)y.z, (bf16_t)y.w};
  *(bf16x8*)(a.d[t] + i8) = o;
}

// ---------------------------------------------------------------------------
// Tiled GEMM: C = A(MxK) * W(NxK)^T, 128x128 tile, BK=32 (m97 structure).
// STORE 2: f32 row-major -> C0.
// STORE 3: fused QKV epilogue (N=3072): cols [0,2048) -> C0 bf16 row-major;
//   [2048,2560) -> Ck bf16 row-major (N=512); [2560,3072) -> Cv transposed
//   (B,KV,DH,L) with bf16x4 packed stores along L.
// ---------------------------------------------------------------------------
template <int STORE>
__global__ __launch_bounds__(256) void gemm_tile(const bf16_t* __restrict__ A,
                                                 const bf16_t* __restrict__ W,
                                                 void* __restrict__ C0,
                                                 bf16_t* __restrict__ Ck,
                                                 bf16_t* __restrict__ Cv,
                                                 int M, int N, int K) {
  __shared__ __align__(16) bf16_t As[128 * 32];
  __shared__ __align__(16) bf16_t Bs[128 * 32];
  const int tid  = threadIdx.x;
  const int lane = tid & 63;
  const int wave = tid >> 6;
  const int l15  = lane & 15;
  const int quad = lane >> 4;
  const int m0 = blockIdx.y * 128;
  const int n0 = blockIdx.x * 128;

  const int srow = wave * 32 + (lane >> 2);
  const int scol = (lane & 3) * 8;
  const bf16_t* ag = A + (size_t)(m0 + srow) * K + scol;
  const bf16_t* wg = W + (size_t)(n0 + srow) * K + scol;
  bf16_t* al = As + wave * 1024;
  bf16_t* bl = Bs + wave * 1024;

  const int wm = (wave >> 1) * 64;
  const int wn = (wave & 1) * 64;

  f32x4 acc[4][4];
#pragma unroll
  for (int mi = 0; mi < 4; mi++)
#pragma unroll
    for (int ni = 0; ni < 4; ni++) acc[mi][ni] = {0.f, 0.f, 0.f, 0.f};

  for (int k0 = 0; k0 < K; k0 += 32) {
    __syncthreads();
    gld16(ag + k0, al);
    gld16(ag + k0 + (size_t)16 * K, al + 512);
    gld16(wg + k0, bl);
    gld16(wg + k0 + (size_t)16 * K, bl + 512);
    __syncthreads();
    bf16x8 af[4], bfr[4];
#pragma unroll
    for (int mi = 0; mi < 4; mi++)
      af[mi] = *(const bf16x8*)(As + (wm + mi * 16 + l15) * 32 + quad * 8);
#pragma unroll
    for (int ni = 0; ni < 4; ni++)
      bfr[ni] = *(const bf16x8*)(Bs + (wn + ni * 16 + l15) * 32 + quad * 8);
#pragma unroll
    for (int mi = 0; mi < 4; mi++)
#pragma unroll
      for (int ni = 0; ni < 4; ni++)
        acc[mi][ni] = mfma16(af[mi], bfr[ni], acc[mi][ni]);
  }

  if (STORE == 2) {
    float* C = (float*)C0;
#pragma unroll
    for (int mi = 0; mi < 4; mi++) {
      const int row = m0 + wm + mi * 16 + quad * 4;
#pragma unroll
      for (int ni = 0; ni < 4; ni++) {
        const int col = n0 + wn + ni * 16 + l15;
#pragma unroll
        for (int i = 0; i < 4; i++)
          C[(size_t)(row + i) * N + col] = acc[mi][ni][i];
      }
    }
  } else {  // STORE == 3
    if (n0 < 2048) {
      bf16_t* C = (bf16_t*)C0;
#pragma unroll
      for (int mi = 0; mi < 4; mi++) {
        const int row = m0 + wm + mi * 16 + quad * 4;
#pragma unroll
        for (int ni = 0; ni < 4; ni++) {
          const int col = n0 + wn + ni * 16 + l15;
#pragma unroll
          for (int i = 0; i < 4; i++)
            C[(size_t)(row + i) * 2048 + col] = (bf16_t)acc[mi][ni][i];
        }
      }
    } else if (n0 < 2560) {
#pragma unroll
      for (int mi = 0; mi < 4; mi++) {
        const int row = m0 + wm + mi * 16 + quad * 4;
#pragma unroll
        for (int ni = 0; ni < 4; ni++) {
          const int col = n0 - 2048 + wn + ni * 16 + l15;
#pragma unroll
          for (int i = 0; i < 4; i++)
            Ck[(size_t)(row + i) * 512 + col] = (bf16_t)acc[mi][ni][i];
        }
      }
    } else {
#pragma unroll
      for (int mi = 0; mi < 4; mi++) {
        const int row = m0 + wm + mi * 16 + quad * 4;
        const int b = row >> 11;
        const int l0 = row & (LL - 1);
#pragma unroll
        for (int ni = 0; ni < 4; ni++) {
          const int kvcol = n0 - 2560 + wn + ni * 16 + l15;
          const int kvh = kvcol >> 7, d = kvcol & 127;
          bf16x4 w4 = {(bf16_t)acc[mi][ni][0], (bf16_t)acc[mi][ni][1],
                       (bf16_t)acc[mi][ni][2], (bf16_t)acc[mi][ni][3]};
          *(bf16x4*)(Cv + ((size_t)(b * HKV + kvh) * DHD + d) * LL + l0) = w4;
        }
      }
    }
  }
}

// In-place RoPE on q,k + padding-bias fill. One thread per (b,l,head,dpair).
__global__ void rope_kernel(bf16_t* __restrict__ q, bf16_t* __restrict__ k,
                            const int* __restrict__ amask, float* __restrict__ bias) {
  const int nq = BB * LL * HQ * 64;
  const int nk = BB * LL * HKV * 64;
  int id = blockIdx.x * blockDim.x + threadIdx.x;
  if (id >= nq + nk) {
    int id2 = id - (nq + nk);
    if (id2 < BB * LL) bias[id2] = (amask[id2] == 0) ? MINV : 0.0f;
    return;
  }
  bf16_t* base;
  int heads, idx;
  if (id < nq) { base = q; heads = HQ; idx = id; }
  else         { base = k; heads = HKV; idx = id - nq; }
  int d = idx & 63; idx >>= 6;
  int hh = idx % heads;
  int bl = idx / heads;      // b*LL + l
  int l = bl & (LL - 1);
  bf16_t* p = base + ((size_t)bl * heads + hh) * DHD + d;
  float x1 = (float)p[0];
  float x2 = (float)p[64];
  // invf = 10000^(-d/64) = exp(-d * ln(10000)/64)
  float invf = __expf(-(float)d * 0.14391156862532788f);
  float fr = (float)l * invf;
  float s, c;
  __sincosf(fr, &s, &c);
  p[0]  = (bf16_t)(x1 * c - x2 * s);
  p[64] = (bf16_t)(x2 * c + x1 * s);
}

// ---------------------------------------------------------------------------
// Flash attention, balanced pairs + LDS staging + frag-major P.
// Block: 256 threads = 4 waves; block c handles 64-row q-tiles {c, 31-c};
// wave w owns rows {c*64+w*16, (31-c)*64+w*16}. KV round = 64 keys in LDS.
// P layout (per wave, per qt, 1 KB per frag): writer lane (quad,l15) stores
// bf16x4 at elem offset f*512 + ((kt&1)*2+(quad>>1))*128 + l15*8 + (quad&1)*4
// (f = kt>>1); reader lane reads B-frag = 16B contiguous at lane*8 (+f*512).
// ---------------------------------------------------------------------------
#define KSTR 136   // K row stride (128 + 8 elements pad)
#define VSTR 72    // V^T row stride (64 + 8 elements pad)

__global__ __launch_bounds__(256, 2) void flash_attn2(const bf16_t* __restrict__ q,
                                                      const bf16_t* __restrict__ k,
                                                      const bf16_t* __restrict__ vt,
                                                      const float* __restrict__ bias,
                                                      bf16_t* __restrict__ o) {
  __shared__ __align__(16) bf16_t Kbuf[64 * KSTR];        // 17.4 KB
  __shared__ __align__(16) bf16_t Vbuf[128 * VSTR];       // 18.4 KB
  __shared__ __align__(16) bf16_t Pbuf[4 * 2 * 1024];     // 16 KB frag-major

  const int tid  = threadIdx.x;
  const int lane = tid & 63;
  const int wave = tid >> 6;
  const int l15  = lane & 15;
  const int quad = lane >> 4;

  const int c  = blockIdx.x >> 5;          // 0..15 : tile pair {c, 31-c}
  const int bh = blockIdx.x & 31;
  const int b  = bh >> 4;
  const int h  = bh & 15;
  const int kv = h >> 2;

  const int q0[2] = { c * 64 + wave * 16, (31 - c) * 64 + wave * 16 };
  const int nrounds = 32 - c;
  const float kScale = 0.08838834764831845f;  // 1/sqrt(128)

  bf16x8 qf[2][4];
#pragma unroll
  for (int qt = 0; qt < 2; qt++) {
    const bf16_t* qb = q + ((size_t)(b * LL + q0[qt] + l15)) * (HQ * DHD) + h * DHD + quad * 8;
#pragma unroll
    for (int t = 0; t < 4; t++) qf[qt][t] = *(const bf16x8*)(qb + 32 * t);
  }

  f32x4 acc[8][2];
#pragma unroll
  for (int mt = 0; mt < 8; mt++)
#pragma unroll
    for (int qt = 0; qt < 2; qt++) acc[mt][qt] = {0.f, 0.f, 0.f, 0.f};
  float m_i[2] = {-1e30f, -1e30f};
  float l_i[2] = {0.f, 0.f};

  const bf16_t* kg_base = k + ((size_t)(b * LL)) * (HKV * DHD) + kv * DHD;
  const bf16_t* vg_base = vt + ((size_t)(b * HKV + kv) * DHD) * LL;
  const float*  bias_b  = bias + b * LL;

  const int krow = tid >> 4, kch = tid & 15;
  const int vrow = tid >> 3, vch = tid & 7;

  for (int r = 0; r < nrounds; r++) {
    const int j0 = r * 64;
    {
      const bf16_t* kg = kg_base + (size_t)(j0 + krow) * (HKV * DHD) + kch * 8;
      const bf16_t* vg = vg_base + (size_t)vrow * LL + j0 + vch * 8;
      bf16x8 kl[4], vl[4];
#pragma unroll
      for (int p = 0; p < 4; p++) kl[p] = *(const bf16x8*)(kg + (size_t)p * 16 * (HKV * DHD));
#pragma unroll
      for (int p = 0; p < 4; p++) vl[p] = *(const bf16x8*)(vg + (size_t)p * 32 * LL);
      __syncthreads();
#pragma unroll
      for (int p = 0; p < 4; p++) *(bf16x8*)(Kbuf + (krow + p * 16) * KSTR + kch * 8) = kl[p];
#pragma unroll
      for (int p = 0; p < 4; p++) *(bf16x8*)(Vbuf + (vrow + p * 32) * VSTR + vch * 8) = vl[p];
      __syncthreads();
    }
    const bool act_a = (r <= c);

    f32x4 s[2][4];
#pragma unroll
    for (int kt = 0; kt < 4; kt++) {
      const bf16_t* kr = Kbuf + (kt * 16 + l15) * KSTR + quad * 8;
      f32x4 s0 = {0.f, 0.f, 0.f, 0.f};
      f32x4 s1 = {0.f, 0.f, 0.f, 0.f};
#pragma unroll
      for (int t = 0; t < 4; t++) {
        bf16x8 kf = *(const bf16x8*)(kr + t * 32);
        if (act_a) s0 = mfma16(kf, qf[0][t], s0);
        s1 = mfma16(kf, qf[1][t], s1);
      }
      s[0][kt] = s0; s[1][kt] = s1;
    }

    f32x4 bv[4];
#pragma unroll
    for (int kt = 0; kt < 4; kt++) bv[kt] = *(const f32x4*)(bias_b + j0 + kt * 16 + quad * 4);

    bf16x8 pf[2][2];
#pragma unroll
    for (int qt = 0; qt < 2; qt++) {
      if (qt == 0 && !act_a) continue;
      const int qrow = q0[qt] + l15;
      const bool diag = (j0 + 63 > q0[qt]);    // mask iff max key > MIN row (R4 fix)
      float mx = -1e30f;
#pragma unroll
      for (int kt = 0; kt < 4; kt++) {
        f32x4 sv = s[qt][kt];
#pragma unroll
        for (int i = 0; i < 4; i++) {
          float x = sv[i] + bv[kt][i];
          if (diag) {
            int key = j0 + kt * 16 + quad * 4 + i;
            if (key > qrow) x = MINV;
          }
          sv[i] = x;
          mx = fmaxf(mx, x);
        }
        s[qt][kt] = sv;
      }
      mx = fmaxf(mx, __shfl_xor(mx, 16));
      mx = fmaxf(mx, __shfl_xor(mx, 32));
      const float mn = fmaxf(m_i[qt], mx);
      const float alpha = __expf((m_i[qt] - mn) * kScale);
      m_i[qt] = mn;
      float sum = 0.f;
      bf16_t* pw = Pbuf + wave * 2048 + qt * 1024 + l15 * 8 + (quad & 1) * 4;
#pragma unroll
      for (int kt = 0; kt < 4; kt++) {
        f32x4 sv = s[qt][kt];
        bf16x4 p4;
#pragma unroll
        for (int i = 0; i < 4; i++) {
          float p = __expf((sv[i] - mn) * kScale);
          sum += p;
          p4[i] = (bf16_t)p;
        }
        *(bf16x4*)(pw + (kt >> 1) * 512 + ((kt & 1) * 2 + (quad >> 1)) * 128) = p4;
      }
      sum += __shfl_xor(sum, 16);
      sum += __shfl_xor(sum, 32);
      l_i[qt] = l_i[qt] * alpha + sum;
#pragma unroll
      for (int mt = 0; mt < 8; mt++) {
        acc[mt][qt][0] *= alpha; acc[mt][qt][1] *= alpha;
        acc[mt][qt][2] *= alpha; acc[mt][qt][3] *= alpha;
      }
      const bf16_t* pr = Pbuf + wave * 2048 + qt * 1024 + lane * 8;
      pf[qt][0] = *(const bf16x8*)(pr);
      pf[qt][1] = *(const bf16x8*)(pr + 512);
    }

#pragma unroll
    for (int mt = 0; mt < 8; mt++) {
      const bf16_t* vr = Vbuf + (mt * 16 + l15) * VSTR + quad * 8;
      bf16x8 vf0 = *(const bf16x8*)(vr);
      bf16x8 vf1 = *(const bf16x8*)(vr + 32);
      if (act_a) {
        acc[mt][0] = mfma16(vf0, pf[0][0], acc[mt][0]);
        acc[mt][0] = mfma16(vf1, pf[0][1], acc[mt][0]);
      }
      acc[mt][1] = mfma16(vf0, pf[1][0], acc[mt][1]);
      acc[mt][1] = mfma16(vf1, pf[1][1], acc[mt][1]);
    }
  }

#pragma unroll
  for (int qt = 0; qt < 2; qt++) {
    const float invl = 1.0f / l_i[qt];
    bf16_t* ob = o + ((size_t)(b * LL + q0[qt] + l15)) * (HQ * DHD) + h * DHD + quad * 4;
#pragma unroll
    for (int mt = 0; mt < 8; mt++) {
      f32x4 a = acc[mt][qt];
      bf16x4 w = {(bf16_t)(a[0] * invl), (bf16_t)(a[1] * invl),
                  (bf16_t)(a[2] * invl), (bf16_t)(a[3] * invl)};
      *(bf16x4*)(ob + mt * 16) = w;
    }
  }
}

extern "C" void kernel_launch(void* const* d_in, const int* in_sizes, int n_in,
                              void* d_out, int out_size, void* d_ws, size_t ws_size,
                              hipStream_t stream) {
  const float* hidden = (const float*)d_in[0];
  const int*   amask  = (const int*)d_in[1];
  const float* Wq     = (const float*)d_in[2];
  const float* Wk     = (const float*)d_in[3];
  const float* Wv     = (const float*)d_in[4];
  const float* Wo     = (const float*)d_in[5];
  float* out = (float*)d_out;

  const int M = BB * LL;           // 4096
  const size_t MB = 1u << 20;
  char* ws = (char*)d_ws;
  bf16_t* hid_b   = (bf16_t*)(ws);            // 16 MB  (B,L,D)
  bf16_t* q_ws    = (bf16_t*)(ws + 16 * MB);  // 16 MB
  bf16_t* attn_ws = (bf16_t*)(ws + 32 * MB);  // 16 MB
  bf16_t* k_ws    = (bf16_t*)(ws + 48 * MB);  //  4 MB
  bf16_t* vt_ws   = (bf16_t*)(ws + 52 * MB);  //  4 MB
  bf16_t* wqkv_b  = (bf16_t*)(ws + 56 * MB);  // 12 MB: Wq(8) + Wk(2) + Wv(2)
  bf16_t* wq_b    = wqkv_b;
  bf16_t* wk_b    = (bf16_t*)(ws + 64 * MB);
  bf16_t* wv_b    = (bf16_t*)(ws + 66 * MB);
  bf16_t* wo_b    = (bf16_t*)(ws + 68 * MB);  //  8 MB
  float*  bias_ws = (float*)(ws);             // 16 KB, aliases hid_b

  CastArgs ca;
  ca.s[0] = hidden; ca.d[0] = hid_b; ca.n[0] = BB * LL * DDIM;
  ca.s[1] = Wq;     ca.d[1] = wq_b;  ca.n[1] = HQ * DHD * DDIM;
  ca.s[2] = Wk;     ca.d[2] = wk_b;  ca.n[2] = HKV * DHD * DDIM;
  ca.s[3] = Wv;     ca.d[3] = wv_b;  ca.n[3] = HKV * DHD * DDIM;
  ca.s[4] = Wo;     ca.d[4] = wo_b;  ca.n[4] = DDIM * DDIM;
  {
    int maxn = BB * LL * DDIM;
    dim3 g((maxn / 8 + 255) / 256, 5);
    cast5_kernel<<<g, 256, 0, stream>>>(ca);
  }

  gemm_tile<3><<<dim3(3072 / 128, M / 128), 256, 0, stream>>>(
      hid_b, wqkv_b, q_ws, k_ws, vt_ws, M, 3072, DDIM);

  {
    int total = BB * LL * (HQ + HKV) * 64 + BB * LL;
    rope_kernel<<<(total + 255) / 256, 256, 0, stream>>>(q_ws, k_ws, amask, bias_ws);
  }

  flash_attn2<<<BB * HQ * 16, 256, 0, stream>>>(q_ws, k_ws, vt_ws, bias_ws, attn_ws);

  gemm_tile<2><<<dim3(DDIM / 128, M / 128), 256, 0, stream>>>(
      attn_ws, wo_b, (void*)out, nullptr, nullptr, M, DDIM, DDIM);
}